// Round 3
// baseline (623.718 us; speedup 1.0000x reference)
//
#include <hip/hip_runtime.h>
#include <stdint.h>

// Round 3: qkv stored per-(window,head): Q[64][32], K[64][32], Vt[32][64] (12KB blocks)
// so the attention kernel's fragment loads are contiguous per lane. QK^T and GEMM2
// upgraded to mfma_f32_16x16x32_bf16; PV stays 16x16x16 (accumulator feeds B-frag
// with zero lane exchange).

typedef __attribute__((ext_vector_type(4))) float f32x4;
typedef __attribute__((ext_vector_type(4))) short s16x4;
typedef __attribute__((ext_vector_type(8))) short s16x8;

#define DEVI static __device__ __forceinline__

DEVI unsigned short f2bf(float f) {
  union { float f; uint32_t u; } v; v.f = f;
  return (unsigned short)((v.u + 0x7FFFu + ((v.u >> 16) & 1u)) >> 16);
}

DEVI f32x4 zero4() { f32x4 z; z[0] = 0.f; z[1] = 0.f; z[2] = 0.f; z[3] = 0.f; return z; }

#if defined(__has_builtin)
#if __has_builtin(__builtin_amdgcn_mfma_f32_16x16x16bf16_1k)
#define MFMA16_BUILTIN 1
#endif
#if __has_builtin(__builtin_amdgcn_global_load_lds)
#define HAS_GLLDS 1
#endif
#endif

DEVI f32x4 mfma16(s16x4 a, s16x4 b, f32x4 c) {
#ifdef MFMA16_BUILTIN
  return __builtin_amdgcn_mfma_f32_16x16x16bf16_1k(a, b, c, 0, 0, 0);
#else
  asm volatile("v_mfma_f32_16x16x16_bf16 %0, %1, %2, %0" : "+v"(c) : "v"(a), "v"(b));
  return c;
#endif
}

DEVI f32x4 mfma32(s16x8 a, s16x8 b, f32x4 c) {
  return __builtin_amdgcn_mfma_f32_16x16x32_bf16(a, b, c, 0, 0, 0);
}

DEVI void stage1k(const unsigned short* g_lane, unsigned short* lds_base, int lane) {
#ifdef HAS_GLLDS
  __builtin_amdgcn_global_load_lds(
      (const __attribute__((address_space(1))) unsigned int*)g_lane,
      (__attribute__((address_space(3))) unsigned int*)lds_base, 16, 0, 0);
#else
  *(s16x8*)(lds_base + lane * 8) = *(const s16x8*)g_lane;
#endif
}

// ---------------- prep kernels ----------------
__global__ void prep_wqkvT(const float* __restrict__ W, unsigned short* __restrict__ WT) {
  int t = blockIdx.x * 256 + threadIdx.x;
  if (t >= 1152 * 384) return;
  int n = t / 384, k = t - n * 384;
  float s = (n < 384) ? 0.17677669529663687f : 1.0f;  // HEAD_DIM^-0.5 folded into Wq
  WT[t] = f2bf(W[(size_t)k * 1152 + n] * s);
}

__global__ void prep_wmT(const float* __restrict__ W, unsigned short* __restrict__ WT) {
  int t = blockIdx.x * 256 + threadIdx.x;
  if (t >= 384 * 384) return;
  int n = t / 384, k = t - n * 384;
  WT[t] = f2bf(W[(size_t)k * 384 + n]);
}

__global__ void prep_bqkv(const float* __restrict__ b, float* __restrict__ bs) {
  int t = blockIdx.x * 256 + threadIdx.x;
  if (t >= 1152) return;
  bs[t] = b[t] * ((t < 384) ? 0.17677669529663687f : 1.0f);
}

// biasT[h][j][i] = bias[h][i][j] = rel_table[relidx(i,j)*12 + h]
__global__ void prep_bias(const float* __restrict__ rel, float* __restrict__ biasT) {
  int t = blockIdx.x * 256 + threadIdx.x;
  if (t >= 12 * 64 * 64) return;
  int h = t >> 12;
  int j = (t >> 6) & 63;
  int i = t & 63;
  int idx = ((i >> 3) - (j >> 3) + 7) * 15 + ((i & 7) - (j & 7) + 7);
  biasT[t] = rel[idx * 12 + h];
}

__global__ void fill_val(float* o, int n, float v) {
  int t = blockIdx.x * 256 + threadIdx.x;
  if (t < n) o[t] = v;
}

// ---------------- x fp32 -> bf16 ----------------
__global__ __launch_bounds__(256) void conv_bf16(const float* __restrict__ x,
                                                 unsigned short* __restrict__ xb) {
  const size_t nchunk = 131072UL * 384 / 8;
  const size_t stride = (size_t)gridDim.x * blockDim.x;
  for (size_t i = (size_t)blockIdx.x * blockDim.x + threadIdx.x; i < nchunk; i += stride) {
    f32x4 a = *(const f32x4*)(x + i * 8);
    f32x4 b = *(const f32x4*)(x + i * 8 + 4);
    s16x8 p;
    p[0] = (short)f2bf(a[0]); p[1] = (short)f2bf(a[1]);
    p[2] = (short)f2bf(a[2]); p[3] = (short)f2bf(a[3]);
    p[4] = (short)f2bf(b[0]); p[5] = (short)f2bf(b[1]);
    p[6] = (short)f2bf(b[2]); p[7] = (short)f2bf(b[3]);
    *(s16x8*)(xb + i * 8) = p;
  }
}

// ---------------- GEMM1: x_bf16[M,384] @ WqkvT^T + bias -> custom qkv layout ----------
// qkv layout: [window][head][{Q,K,Vt}]: Q[64][32], K[64][32], Vt[32][64], 2048 elems each.
__global__ __launch_bounds__(256) void gemm1_k(const unsigned short* __restrict__ A,
                                               const unsigned short* __restrict__ BT,
                                               const float* __restrict__ bias,
                                               unsigned short* __restrict__ qkv) {
  constexpr int K = 384;
  __shared__ unsigned short As[128 * 64];
  __shared__ unsigned short Bs[128 * 64];
  const int tid = threadIdx.x;
  const int lane = tid & 63, wv = tid >> 6;
  const int n0 = blockIdx.x * 128, m0 = blockIdx.y * 128;
  const int wr = wv >> 1, wc = wv & 1;
  const int lg = lane >> 4, lr = lane & 15;

  const unsigned short* Ag = A + (size_t)(m0 + wv * 32 + (lane >> 3)) * K + (lane & 7) * 8;
  const unsigned short* Bg = BT + (size_t)(n0 + wv * 32 + (lane >> 3)) * K + (lane & 7) * 8;

  f32x4 acc[4][4];
#pragma unroll
  for (int i = 0; i < 4; ++i)
#pragma unroll
    for (int j = 0; j < 4; ++j) acc[i][j] = zero4();

  for (int k0 = 0; k0 < K; k0 += 64) {
#pragma unroll
    for (int c = 0; c < 4; ++c)
      stage1k(Ag + (size_t)(c * 8) * K + k0, &As[(wv * 32 + c * 8) * 64], lane);
#pragma unroll
    for (int c = 0; c < 4; ++c)
      stage1k(Bg + (size_t)(c * 8) * K + k0, &Bs[(wv * 32 + c * 8) * 64], lane);
    __syncthreads();
#pragma unroll
    for (int kk = 0; kk < 64; kk += 32) {
      s16x8 af[4], bf[4];
#pragma unroll
      for (int mt = 0; mt < 4; ++mt)
        af[mt] = *(const s16x8*)&As[(wr * 64 + 16 * mt + lr) * 64 + kk + 8 * lg];
#pragma unroll
      for (int nt = 0; nt < 4; ++nt)
        bf[nt] = *(const s16x8*)&Bs[(wc * 64 + 16 * nt + lr) * 64 + kk + 8 * lg];
#pragma unroll
      for (int mt = 0; mt < 4; ++mt)
#pragma unroll
        for (int nt = 0; nt < 4; ++nt)
          acc[mt][nt] = mfma32(af[mt], bf[nt], acc[mt][nt]);
    }
    __syncthreads();
  }

  // epilogue -> custom layout. sel is block-uniform (1152 = 9*128, 384 = 3*128).
  const int sel = n0 / 384;
  const int crow = m0 + wr * 64 + 4 * lg;     // global token index
  const int window = crow >> 6;               // wave-uniform (m0/64 + wr)
  const int t0 = crow & 63;                   // 4*lg
  const int ccol = n0 + wc * 64 + lr;
#pragma unroll
  for (int nt = 0; nt < 4; ++nt) {
    const int col = ccol + 16 * nt;
    const int hcol = col - sel * 384;
    const int h = hcol >> 5, d = hcol & 31;
    const float bv = bias[col];
    unsigned short* base = qkv + (((size_t)window * 12 + h) * 3 + sel) * 2048;
#pragma unroll
    for (int mt = 0; mt < 4; ++mt) {
      if (sel < 2) {
#pragma unroll
        for (int e = 0; e < 4; ++e)
          base[(t0 + 16 * mt + e) * 32 + d] = f2bf(acc[mt][nt][e] + bv);
      } else {
        s16x4 pk;
#pragma unroll
        for (int e = 0; e < 4; ++e) pk[e] = (short)f2bf(acc[mt][nt][e] + bv);
        *(s16x4*)&base[d * 64 + t0 + 16 * mt] = pk;
      }
    }
  }
}

// ---------------- fused attention + GEMM2, one block (4 waves) per window ----------
__global__ __launch_bounds__(256) void attn_gemm2_k(const unsigned short* __restrict__ qkv,
                                                    const float* __restrict__ biasT,
                                                    const unsigned short* __restrict__ WmT,
                                                    const float* __restrict__ bm,
                                                    float* __restrict__ out) {
  __shared__ unsigned short att_s[64 * 392];
  const int lane = threadIdx.x & 63;
  const int wv = threadIdx.x >> 6;
  const int bg = blockIdx.x;  // window index [0, 2048)
  const int lg = lane >> 4, lr = lane & 15;

#pragma unroll 1
  for (int hi = 0; hi < 3; ++hi) {
    const int h = wv * 3 + hi;
    const unsigned short* hb = qkv + ((size_t)bg * 12 + h) * 3 * 2048;
    const unsigned short* Qh = hb;
    const unsigned short* Kh = hb + 2048;
    const unsigned short* Vth = hb + 4096;

    // S^T = K * Q^T via 16x16x32 (k-dim = DH = 32, single kstep)
    s16x8 ka[4], qb[4];
#pragma unroll
    for (int jt = 0; jt < 4; ++jt)
      ka[jt] = *(const s16x8*)&Kh[(jt * 16 + lr) * 32 + 8 * lg];
#pragma unroll
    for (int it = 0; it < 4; ++it)
      qb[it] = *(const s16x8*)&Qh[(it * 16 + lr) * 32 + 8 * lg];

    f32x4 c[4][4];
#pragma unroll
    for (int a = 0; a < 4; ++a)
#pragma unroll
      for (int b2 = 0; b2 < 4; ++b2) c[a][b2] = zero4();

#pragma unroll
    for (int jt = 0; jt < 4; ++jt)
#pragma unroll
      for (int it = 0; it < 4; ++it)
        c[jt][it] = mfma32(ka[jt], qb[it], c[jt][it]);

    // bias: S^T[j][i] += bias[h][i][j]; j = jt*16+4*lg+e, i = it*16+lr
#pragma unroll
    for (int jt = 0; jt < 4; ++jt)
#pragma unroll
      for (int it = 0; it < 4; ++it) {
        const float* bp = biasT + h * 4096 + (jt * 16 + lg * 4) * 64 + it * 16 + lr;
#pragma unroll
        for (int e = 0; e < 4; ++e) c[jt][it][e] += bp[e * 64];
      }

    // softmax over j per column i; lanes sharing i: {l, l^16, l^32, l^48}
    s16x4 pb[4][4];
#pragma unroll
    for (int it = 0; it < 4; ++it) {
      float m = -3.0e38f;
#pragma unroll
      for (int jt = 0; jt < 4; ++jt)
#pragma unroll
        for (int e = 0; e < 4; ++e) m = fmaxf(m, c[jt][it][e]);
      m = fmaxf(m, __shfl_xor(m, 16));
      m = fmaxf(m, __shfl_xor(m, 32));
      float s = 0.f;
#pragma unroll
      for (int jt = 0; jt < 4; ++jt)
#pragma unroll
        for (int e = 0; e < 4; ++e) {
          float p = __expf(c[jt][it][e] - m);
          c[jt][it][e] = p;
          s += p;
        }
      s += __shfl_xor(s, 16);
      s += __shfl_xor(s, 32);
      const float inv = 1.f / s;
#pragma unroll
      for (int jt = 0; jt < 4; ++jt) {
        s16x4 pk;
#pragma unroll
        for (int e = 0; e < 4; ++e) pk[e] = (short)f2bf(c[jt][it][e] * inv);
        pb[jt][it] = pk;
      }
    }

    // O^T = V^T * P^T (16x16x16; pb feeds B-frag with zero lane exchange)
    f32x4 o[2][4];
#pragma unroll
    for (int a = 0; a < 2; ++a)
#pragma unroll
      for (int b2 = 0; b2 < 4; ++b2) o[a][b2] = zero4();

#pragma unroll
    for (int jt = 0; jt < 4; ++jt) {
      s16x4 va[2];
#pragma unroll
      for (int dt = 0; dt < 2; ++dt)
        va[dt] = *(const s16x4*)&Vth[(dt * 16 + lr) * 64 + jt * 16 + 4 * lg];
#pragma unroll
      for (int dt = 0; dt < 2; ++dt)
#pragma unroll
        for (int it = 0; it < 4; ++it)
          o[dt][it] = mfma16(va[dt], pb[jt][it], o[dt][it]);
    }

    // O^T[d][i]: d = dt*16+4*lg+e, i = it*16+lr  ->  att_s[i][h*32+d]
#pragma unroll
    for (int dt = 0; dt < 2; ++dt)
#pragma unroll
      for (int it = 0; it < 4; ++it) {
        s16x4 pk;
#pragma unroll
        for (int e = 0; e < 4; ++e) pk[e] = (short)f2bf(o[dt][it][e]);
        *(s16x4*)&att_s[(it * 16 + lr) * 392 + h * 32 + dt * 16 + 4 * lg] = pk;
      }
  }

  __syncthreads();

  // Phase 2: out[64,384] = att_s @ Wm + bm ; wave wv -> cols [wv*96, wv*96+96)
  f32x4 acc[4][6];
#pragma unroll
  for (int mt = 0; mt < 4; ++mt)
#pragma unroll
    for (int nt = 0; nt < 6; ++nt) acc[mt][nt] = zero4();

  const int n0w = wv * 96;
#pragma unroll 2
  for (int ks = 0; ks < 12; ++ks) {
    s16x8 af[4], bfr[6];
#pragma unroll
    for (int mt = 0; mt < 4; ++mt)
      af[mt] = *(const s16x8*)&att_s[(16 * mt + lr) * 392 + ks * 32 + 8 * lg];
#pragma unroll
    for (int nt = 0; nt < 6; ++nt)
      bfr[nt] = *(const s16x8*)&WmT[(size_t)(n0w + 16 * nt + lr) * 384 + ks * 32 + 8 * lg];
#pragma unroll
    for (int mt = 0; mt < 4; ++mt)
#pragma unroll
      for (int nt = 0; nt < 6; ++nt)
        acc[mt][nt] = mfma32(af[mt], bfr[nt], acc[mt][nt]);
  }

  float* ob = out + (size_t)bg * 64 * 384;
#pragma unroll
  for (int mt = 0; mt < 4; ++mt)
#pragma unroll
    for (int nt = 0; nt < 6; ++nt) {
      const int col = n0w + 16 * nt + lr;
      const float bv = bm[col];
#pragma unroll
      for (int e = 0; e < 4; ++e)
        ob[(size_t)(16 * mt + 4 * lg + e) * 384 + col] = acc[mt][nt][e] + bv;
    }
}

extern "C" void kernel_launch(void* const* d_in, const int* in_sizes, int n_in,
                              void* d_out, int out_size, void* d_ws, size_t ws_size,
                              hipStream_t stream) {
  const float* x = (const float*)d_in[0];
  const float* Wqkv = (const float*)d_in[1];
  const float* bqkv = (const float*)d_in[2];
  const float* Wm = (const float*)d_in[3];
  const float* bm = (const float*)d_in[4];
  const float* rel = (const float*)d_in[5];

  const size_t M = 131072;  // B*G*P
  char* ws = (char*)d_ws;
  size_t off = 0;
  unsigned short* qkv = (unsigned short*)(ws + off);   off += M * 1152 * 2;  // 302 MB
  unsigned short* xb = (unsigned short*)(ws + off);    off += M * 384 * 2;   // 100 MB
  unsigned short* WqkvT = (unsigned short*)(ws + off); off += 1152 * 384 * 2;
  unsigned short* WmT = (unsigned short*)(ws + off);   off += 384 * 384 * 2;
  float* biasT = (float*)(ws + off);                   off += 12 * 64 * 64 * 4;
  float* bqkvs = (float*)(ws + off);                   off += 1152 * 4;

  if (ws_size < off) {
    fill_val<<<(out_size + 255) / 256, 256, 0, stream>>>((float*)d_out, out_size, 12345.0f);
    return;
  }

  prep_wqkvT<<<(1152 * 384 + 255) / 256, 256, 0, stream>>>(Wqkv, WqkvT);
  prep_wmT<<<(384 * 384 + 255) / 256, 256, 0, stream>>>(Wm, WmT);
  prep_bqkv<<<5, 256, 0, stream>>>(bqkv, bqkvs);
  prep_bias<<<(12 * 64 * 64 + 255) / 256, 256, 0, stream>>>(rel, biasT);
  conv_bf16<<<2048, 256, 0, stream>>>(x, xb);

  gemm1_k<<<dim3(9, 1024), 256, 0, stream>>>(xb, WqkvT, bqkvs, qkv);
  attn_gemm2_k<<<2048, 256, 0, stream>>>(qkv, biasT, WmT, bm, (float*)d_out);
}

// Round 4
// 522.852 us; speedup vs baseline: 1.1929x; 1.1929x over previous
//
#include <hip/hip_runtime.h>
#include <stdint.h>

// Round 4: UN-fuse attention and GEMM2 (R2 fusion was a latency-bound regression:
// MfmaUtil 7.6%, everything idle). attn_k = one wave per (window,head), zero
// LDS/barriers, per-lane-fragment bias table (one f32x4 load per tile).
// GEMM2 = m97-pattern GEMM (same body as GEMM1). XCD swizzle on both GEMMs.

typedef __attribute__((ext_vector_type(4))) float f32x4;
typedef __attribute__((ext_vector_type(4))) short s16x4;
typedef __attribute__((ext_vector_type(8))) short s16x8;

#define DEVI static __device__ __forceinline__

DEVI unsigned short f2bf(float f) {
  union { float f; uint32_t u; } v; v.f = f;
  return (unsigned short)((v.u + 0x7FFFu + ((v.u >> 16) & 1u)) >> 16);
}

DEVI f32x4 zero4() { f32x4 z; z[0] = 0.f; z[1] = 0.f; z[2] = 0.f; z[3] = 0.f; return z; }

#if defined(__has_builtin)
#if __has_builtin(__builtin_amdgcn_mfma_f32_16x16x16bf16_1k)
#define MFMA16_BUILTIN 1
#endif
#if __has_builtin(__builtin_amdgcn_global_load_lds)
#define HAS_GLLDS 1
#endif
#endif

DEVI f32x4 mfma16(s16x4 a, s16x4 b, f32x4 c) {
#ifdef MFMA16_BUILTIN
  return __builtin_amdgcn_mfma_f32_16x16x16bf16_1k(a, b, c, 0, 0, 0);
#else
  asm volatile("v_mfma_f32_16x16x16_bf16 %0, %1, %2, %0" : "+v"(c) : "v"(a), "v"(b));
  return c;
#endif
}

DEVI f32x4 mfma32(s16x8 a, s16x8 b, f32x4 c) {
  return __builtin_amdgcn_mfma_f32_16x16x32_bf16(a, b, c, 0, 0, 0);
}

DEVI void stage1k(const unsigned short* g_lane, unsigned short* lds_base) {
#ifdef HAS_GLLDS
  __builtin_amdgcn_global_load_lds(
      (const __attribute__((address_space(1))) unsigned int*)g_lane,
      (__attribute__((address_space(3))) unsigned int*)lds_base, 16, 0, 0);
#else
  *(s16x8*)(lds_base + (threadIdx.x & 63) * 8) = *(const s16x8*)g_lane;
#endif
}

// ---------------- prep kernels ----------------
__global__ void prep_wqkvT(const float* __restrict__ W, unsigned short* __restrict__ WT) {
  int t = blockIdx.x * 256 + threadIdx.x;
  if (t >= 1152 * 384) return;
  int n = t / 384, k = t - n * 384;
  float s = (n < 384) ? 0.17677669529663687f : 1.0f;  // HEAD_DIM^-0.5 folded into Wq
  WT[t] = f2bf(W[(size_t)k * 1152 + n] * s);
}

__global__ void prep_wmT(const float* __restrict__ W, unsigned short* __restrict__ WT) {
  int t = blockIdx.x * 256 + threadIdx.x;
  if (t >= 384 * 384) return;
  int n = t / 384, k = t - n * 384;
  WT[t] = f2bf(W[(size_t)k * 384 + n]);
}

__global__ void prep_bqkv(const float* __restrict__ b, float* __restrict__ bs) {
  int t = blockIdx.x * 256 + threadIdx.x;
  if (t >= 1152) return;
  bs[t] = b[t] * ((t < 384) ? 0.17677669529663687f : 1.0f);
}

// biasF: per-lane fragment order. biasF[((h*16 + jt*4 + it)*64 + lane)*4 + e]
//      = bias[h][i][j], i = it*16+lr, j = jt*16+lg*4+e  (lg=lane>>4, lr=lane&15)
__global__ void prep_biasF(const float* __restrict__ rel, float* __restrict__ biasF) {
  int t = blockIdx.x * 256 + threadIdx.x;  // 12*16*64 = 12288
  if (t >= 12288) return;
  int h = t >> 10;
  int r = (t >> 6) & 15;
  int lane = t & 63;
  int jt = r >> 2, it = r & 3;
  int lg = lane >> 4, lr = lane & 15;
  int i = it * 16 + lr;
#pragma unroll
  for (int e = 0; e < 4; ++e) {
    int j = jt * 16 + lg * 4 + e;
    int idx = ((i >> 3) - (j >> 3) + 7) * 15 + ((i & 7) - (j & 7) + 7);
    biasF[t * 4 + e] = rel[idx * 12 + h];
  }
}

__global__ void fill_val(float* o, int n, float v) {
  int t = blockIdx.x * 256 + threadIdx.x;
  if (t < n) o[t] = v;
}

// ---------------- x fp32 -> bf16 ----------------
__global__ __launch_bounds__(256) void conv_bf16(const float* __restrict__ x,
                                                 unsigned short* __restrict__ xb) {
  const size_t nchunk = 131072UL * 384 / 8;
  const size_t stride = (size_t)gridDim.x * blockDim.x;
  for (size_t i = (size_t)blockIdx.x * blockDim.x + threadIdx.x; i < nchunk; i += stride) {
    f32x4 a = *(const f32x4*)(x + i * 8);
    f32x4 b = *(const f32x4*)(x + i * 8 + 4);
    s16x8 p;
    p[0] = (short)f2bf(a[0]); p[1] = (short)f2bf(a[1]);
    p[2] = (short)f2bf(a[2]); p[3] = (short)f2bf(a[3]);
    p[4] = (short)f2bf(b[0]); p[5] = (short)f2bf(b[1]);
    p[6] = (short)f2bf(b[2]); p[7] = (short)f2bf(b[3]);
    *(s16x8*)(xb + i * 8) = p;
  }
}

// ---------------- GEMM (m97 pattern), templated epilogue ----------------
// QKV_EPI=true : N=1152, writes custom qkv layout [window][head]{Q[64][32],K[64][32],Vt[32][64]}
// QKV_EPI=false: N=384, plain fp32 row-major out + bias.
template <bool QKV_EPI>
__global__ __launch_bounds__(256) void gemm_k(const unsigned short* __restrict__ A,
                                              const unsigned short* __restrict__ BT,
                                              const float* __restrict__ bias,
                                              void* __restrict__ Cv) {
  constexpr int K = 384;
  constexpr int NT = QKV_EPI ? 9 : 3;
  constexpr int N = NT * 128;
  __shared__ unsigned short As[128 * 64];
  __shared__ unsigned short Bs[128 * 64];
  // XCD-aware bijective swizzle: nwg = NT*1024 (divisible by 8)
  const int bid = blockIdx.x;
  const int swz = (bid & 7) * (NT * 128) + (bid >> 3);
  const int n0 = (swz % NT) * 128;
  const int m0 = (swz / NT) * 128;
  const int tid = threadIdx.x;
  const int lane = tid & 63, wv = tid >> 6;
  const int wr = wv >> 1, wc = wv & 1;
  const int lg = lane >> 4, lr = lane & 15;

  const unsigned short* Ag = A + (size_t)(m0 + wv * 32 + (lane >> 3)) * K + (lane & 7) * 8;
  const unsigned short* Bg = BT + (size_t)(n0 + wv * 32 + (lane >> 3)) * K + (lane & 7) * 8;

  f32x4 acc[4][4];
#pragma unroll
  for (int i = 0; i < 4; ++i)
#pragma unroll
    for (int j = 0; j < 4; ++j) acc[i][j] = zero4();

  for (int k0 = 0; k0 < K; k0 += 64) {
#pragma unroll
    for (int c = 0; c < 4; ++c)
      stage1k(Ag + (size_t)(c * 8) * K + k0, &As[(wv * 32 + c * 8) * 64]);
#pragma unroll
    for (int c = 0; c < 4; ++c)
      stage1k(Bg + (size_t)(c * 8) * K + k0, &Bs[(wv * 32 + c * 8) * 64]);
    __syncthreads();
#pragma unroll
    for (int kk = 0; kk < 64; kk += 32) {
      s16x8 af[4], bf[4];
#pragma unroll
      for (int mt = 0; mt < 4; ++mt)
        af[mt] = *(const s16x8*)&As[(wr * 64 + 16 * mt + lr) * 64 + kk + 8 * lg];
#pragma unroll
      for (int nt = 0; nt < 4; ++nt)
        bf[nt] = *(const s16x8*)&Bs[(wc * 64 + 16 * nt + lr) * 64 + kk + 8 * lg];
#pragma unroll
      for (int mt = 0; mt < 4; ++mt)
#pragma unroll
        for (int nt = 0; nt < 4; ++nt)
          acc[mt][nt] = mfma32(af[mt], bf[nt], acc[mt][nt]);
    }
    __syncthreads();
  }

  const int crow = m0 + wr * 64 + 4 * lg;
  const int ccol = n0 + wc * 64 + lr;
  if constexpr (QKV_EPI) {
    const int sel = n0 / 384;          // block-uniform (head dim 32 | 128)
    const int window = crow >> 6;      // wave-uniform
    const int t0 = crow & 63;
    unsigned short* qkv = (unsigned short*)Cv;
#pragma unroll
    for (int nt = 0; nt < 4; ++nt) {
      const int col = ccol + 16 * nt;
      const int hcol = col - sel * 384;
      const int h = hcol >> 5, d = hcol & 31;
      const float bv = bias[col];
      unsigned short* base = qkv + (((size_t)window * 12 + h) * 3 + sel) * 2048;
#pragma unroll
      for (int mt = 0; mt < 4; ++mt) {
        if (sel < 2) {
#pragma unroll
          for (int e = 0; e < 4; ++e)
            base[(t0 + 16 * mt + e) * 32 + d] = f2bf(acc[mt][nt][e] + bv);
        } else {
          s16x4 pk;
#pragma unroll
          for (int e = 0; e < 4; ++e) pk[e] = (short)f2bf(acc[mt][nt][e] + bv);
          *(s16x4*)&base[d * 64 + t0 + 16 * mt] = pk;
        }
      }
    }
  } else {
    float* C = (float*)Cv;
#pragma unroll
    for (int mt = 0; mt < 4; ++mt)
#pragma unroll
      for (int nt = 0; nt < 4; ++nt) {
        const int col = ccol + 16 * nt;
        const float bv = bias[col];
#pragma unroll
        for (int e = 0; e < 4; ++e)
          C[(size_t)(crow + 16 * mt + e) * N + col] = acc[mt][nt][e] + bv;
      }
  }
}

// ---------------- attention: one wave per (window, head), no LDS ----------------
__global__ __launch_bounds__(256) void attn_k(const unsigned short* __restrict__ qkv,
                                              const float* __restrict__ biasF,
                                              unsigned short* __restrict__ attnout) {
  const int lane = threadIdx.x & 63;
  const int wv = threadIdx.x >> 6;
  const int wh = blockIdx.x * 4 + wv;  // [0, 24576)
  const int window = wh / 12;
  const int h = wh - window * 12;
  const int lg = lane >> 4, lr = lane & 15;

  const unsigned short* hb = qkv + (size_t)wh * 6144;
  const unsigned short* Qh = hb;
  const unsigned short* Kh = hb + 2048;
  const unsigned short* Vth = hb + 4096;

  // S^T = K * Q^T via 16x16x32 (k-dim = DH = 32)
  s16x8 ka[4], qb[4];
#pragma unroll
  for (int jt = 0; jt < 4; ++jt)
    ka[jt] = *(const s16x8*)&Kh[(jt * 16 + lr) * 32 + 8 * lg];
#pragma unroll
  for (int it = 0; it < 4; ++it)
    qb[it] = *(const s16x8*)&Qh[(it * 16 + lr) * 32 + 8 * lg];

  f32x4 c[4][4];
#pragma unroll
  for (int a = 0; a < 4; ++a)
#pragma unroll
    for (int b2 = 0; b2 < 4; ++b2) c[a][b2] = zero4();

#pragma unroll
  for (int jt = 0; jt < 4; ++jt)
#pragma unroll
    for (int it = 0; it < 4; ++it)
      c[jt][it] = mfma32(ka[jt], qb[it], c[jt][it]);

  // bias: one coalesced f32x4 per (jt,it), in exact fragment order
  const f32x4* bF = (const f32x4*)biasF + ((size_t)h * 16) * 64 + lane;
#pragma unroll
  for (int jt = 0; jt < 4; ++jt)
#pragma unroll
    for (int it = 0; it < 4; ++it)
      c[jt][it] += bF[(jt * 4 + it) * 64];

  // softmax over j per column i; lanes sharing i: {l, l^16, l^32, l^48}
  s16x4 pb[4][4];
#pragma unroll
  for (int it = 0; it < 4; ++it) {
    float m = -3.0e38f;
#pragma unroll
    for (int jt = 0; jt < 4; ++jt)
#pragma unroll
      for (int e = 0; e < 4; ++e) m = fmaxf(m, c[jt][it][e]);
    m = fmaxf(m, __shfl_xor(m, 16));
    m = fmaxf(m, __shfl_xor(m, 32));
    float s = 0.f;
#pragma unroll
    for (int jt = 0; jt < 4; ++jt)
#pragma unroll
      for (int e = 0; e < 4; ++e) {
        float p = __expf(c[jt][it][e] - m);
        c[jt][it][e] = p;
        s += p;
      }
    s += __shfl_xor(s, 16);
    s += __shfl_xor(s, 32);
    const float inv = 1.f / s;
#pragma unroll
    for (int jt = 0; jt < 4; ++jt) {
      s16x4 pk;
#pragma unroll
      for (int e = 0; e < 4; ++e) pk[e] = (short)f2bf(c[jt][it][e] * inv);
      pb[jt][it] = pk;
    }
  }

  // O^T = V^T * P^T (16x16x16; pb feeds B-frag with zero lane exchange)
  f32x4 o[2][4];
#pragma unroll
  for (int a = 0; a < 2; ++a)
#pragma unroll
    for (int b2 = 0; b2 < 4; ++b2) o[a][b2] = zero4();

#pragma unroll
  for (int jt = 0; jt < 4; ++jt) {
    s16x4 va[2];
#pragma unroll
    for (int dt = 0; dt < 2; ++dt)
      va[dt] = *(const s16x4*)&Vth[(dt * 16 + lr) * 64 + jt * 16 + 4 * lg];
#pragma unroll
    for (int dt = 0; dt < 2; ++dt)
#pragma unroll
      for (int it = 0; it < 4; ++it)
        o[dt][it] = mfma16(va[dt], pb[jt][it], o[dt][it]);
  }

  // O^T[d][i]: d = dt*16+4*lg+e, i = it*16+lr  ->  attnout[window*64+i][h*32+d]
  unsigned short* ob = attnout + (size_t)window * 64 * 384;
#pragma unroll
  for (int dt = 0; dt < 2; ++dt)
#pragma unroll
    for (int it = 0; it < 4; ++it) {
      s16x4 pk;
#pragma unroll
      for (int e = 0; e < 4; ++e) pk[e] = (short)f2bf(o[dt][it][e]);
      *(s16x4*)&ob[(size_t)(it * 16 + lr) * 384 + h * 32 + dt * 16 + 4 * lg] = pk;
    }
}

extern "C" void kernel_launch(void* const* d_in, const int* in_sizes, int n_in,
                              void* d_out, int out_size, void* d_ws, size_t ws_size,
                              hipStream_t stream) {
  const float* x = (const float*)d_in[0];
  const float* Wqkv = (const float*)d_in[1];
  const float* bqkv = (const float*)d_in[2];
  const float* Wm = (const float*)d_in[3];
  const float* bm = (const float*)d_in[4];
  const float* rel = (const float*)d_in[5];

  const size_t M = 131072;  // B*G*P
  char* ws = (char*)d_ws;
  size_t off = 0;
  unsigned short* qkv = (unsigned short*)(ws + off);   off += M * 1152 * 2;  // 302 MB
  unsigned short* xb = (unsigned short*)(ws + off);    off += M * 384 * 2;   // 100 MB (reused as attnout)
  unsigned short* WqkvT = (unsigned short*)(ws + off); off += 1152 * 384 * 2;
  unsigned short* WmT = (unsigned short*)(ws + off);   off += 384 * 384 * 2;
  float* biasF = (float*)(ws + off);                   off += 12 * 16 * 64 * 4 * 4;
  float* bqkvs = (float*)(ws + off);                   off += 1152 * 4;
  unsigned short* attnout = xb;  // xb is dead after gemm1

  if (ws_size < off) {
    fill_val<<<(out_size + 255) / 256, 256, 0, stream>>>((float*)d_out, out_size, 12345.0f);
    return;
  }

  prep_wqkvT<<<(1152 * 384 + 255) / 256, 256, 0, stream>>>(Wqkv, WqkvT);
  prep_wmT<<<(384 * 384 + 255) / 256, 256, 0, stream>>>(Wm, WmT);
  prep_bqkv<<<5, 256, 0, stream>>>(bqkv, bqkvs);
  prep_biasF<<<48, 256, 0, stream>>>(rel, biasF);
  conv_bf16<<<2048, 256, 0, stream>>>(x, xb);

  gemm_k<true><<<9216, 256, 0, stream>>>(xb, WqkvT, bqkvs, qkv);
  attn_k<<<6144, 256, 0, stream>>>(qkv, biasF, attnout);
  gemm_k<false><<<3072, 256, 0, stream>>>(attnout, WmT, bm, d_out);
}

// Round 5
// 485.589 us; speedup vs baseline: 1.2845x; 1.0767x over previous
//
#include <hip/hip_runtime.h>
#include <stdint.h>

// Round 5: gemm_k gets (a) double-buffered LDS with counted s_waitcnt vmcnt(8)
// across raw s_barrier (T3-min pipeline: loads stay in flight across barriers),
// (b) LDS-staged coalesced epilogue for Q/K parts (swizzled 32KB tile, 16B
// stores, dense 64B head-rows). attn_k unchanged from R4 (passing).

typedef __attribute__((ext_vector_type(4))) float f32x4;
typedef __attribute__((ext_vector_type(4))) short s16x4;
typedef __attribute__((ext_vector_type(8))) short s16x8;

#define DEVI static __device__ __forceinline__

DEVI unsigned short f2bf(float f) {
  union { float f; uint32_t u; } v; v.f = f;
  return (unsigned short)((v.u + 0x7FFFu + ((v.u >> 16) & 1u)) >> 16);
}

DEVI f32x4 zero4() { f32x4 z; z[0] = 0.f; z[1] = 0.f; z[2] = 0.f; z[3] = 0.f; return z; }

#if defined(__has_builtin)
#if __has_builtin(__builtin_amdgcn_mfma_f32_16x16x16bf16_1k)
#define MFMA16_BUILTIN 1
#endif
#if __has_builtin(__builtin_amdgcn_global_load_lds)
#define HAS_GLLDS 1
#endif
#endif

DEVI f32x4 mfma16(s16x4 a, s16x4 b, f32x4 c) {
#ifdef MFMA16_BUILTIN
  return __builtin_amdgcn_mfma_f32_16x16x16bf16_1k(a, b, c, 0, 0, 0);
#else
  asm volatile("v_mfma_f32_16x16x16_bf16 %0, %1, %2, %0" : "+v"(c) : "v"(a), "v"(b));
  return c;
#endif
}

DEVI f32x4 mfma32(s16x8 a, s16x8 b, f32x4 c) {
  return __builtin_amdgcn_mfma_f32_16x16x32_bf16(a, b, c, 0, 0, 0);
}

DEVI void stage1k(const unsigned short* g_lane, unsigned short* lds_base) {
#ifdef HAS_GLLDS
  __builtin_amdgcn_global_load_lds(
      (const __attribute__((address_space(1))) unsigned int*)g_lane,
      (__attribute__((address_space(3))) unsigned int*)lds_base, 16, 0, 0);
#else
  *(s16x8*)(lds_base + (threadIdx.x & 63) * 8) = *(const s16x8*)g_lane;
#endif
}

// ---------------- prep kernels ----------------
__global__ void prep_wqkvT(const float* __restrict__ W, unsigned short* __restrict__ WT) {
  int t = blockIdx.x * 256 + threadIdx.x;
  if (t >= 1152 * 384) return;
  int n = t / 384, k = t - n * 384;
  float s = (n < 384) ? 0.17677669529663687f : 1.0f;  // HEAD_DIM^-0.5 folded into Wq
  WT[t] = f2bf(W[(size_t)k * 1152 + n] * s);
}

__global__ void prep_wmT(const float* __restrict__ W, unsigned short* __restrict__ WT) {
  int t = blockIdx.x * 256 + threadIdx.x;
  if (t >= 384 * 384) return;
  int n = t / 384, k = t - n * 384;
  WT[t] = f2bf(W[(size_t)k * 384 + n]);
}

__global__ void prep_bqkv(const float* __restrict__ b, float* __restrict__ bs) {
  int t = blockIdx.x * 256 + threadIdx.x;
  if (t >= 1152) return;
  bs[t] = b[t] * ((t < 384) ? 0.17677669529663687f : 1.0f);
}

// biasF: per-lane fragment order. biasF[((h*16 + jt*4 + it)*64 + lane)*4 + e]
__global__ void prep_biasF(const float* __restrict__ rel, float* __restrict__ biasF) {
  int t = blockIdx.x * 256 + threadIdx.x;  // 12*16*64 = 12288
  if (t >= 12288) return;
  int h = t >> 10;
  int r = (t >> 6) & 15;
  int lane = t & 63;
  int jt = r >> 2, it = r & 3;
  int lg = lane >> 4, lr = lane & 15;
  int i = it * 16 + lr;
#pragma unroll
  for (int e = 0; e < 4; ++e) {
    int j = jt * 16 + lg * 4 + e;
    int idx = ((i >> 3) - (j >> 3) + 7) * 15 + ((i & 7) - (j & 7) + 7);
    biasF[t * 4 + e] = rel[idx * 12 + h];
  }
}

__global__ void fill_val(float* o, int n, float v) {
  int t = blockIdx.x * 256 + threadIdx.x;
  if (t < n) o[t] = v;
}

// ---------------- x fp32 -> bf16 ----------------
__global__ __launch_bounds__(256) void conv_bf16(const float* __restrict__ x,
                                                 unsigned short* __restrict__ xb) {
  const size_t nchunk = 131072UL * 384 / 8;
  const size_t stride = (size_t)gridDim.x * blockDim.x;
  for (size_t i = (size_t)blockIdx.x * blockDim.x + threadIdx.x; i < nchunk; i += stride) {
    f32x4 a = *(const f32x4*)(x + i * 8);
    f32x4 b = *(const f32x4*)(x + i * 8 + 4);
    s16x8 p;
    p[0] = (short)f2bf(a[0]); p[1] = (short)f2bf(a[1]);
    p[2] = (short)f2bf(a[2]); p[3] = (short)f2bf(a[3]);
    p[4] = (short)f2bf(b[0]); p[5] = (short)f2bf(b[1]);
    p[6] = (short)f2bf(b[2]); p[7] = (short)f2bf(b[3]);
    *(s16x8*)(xb + i * 8) = p;
  }
}

// ---------------- GEMM (dbuf + counted vmcnt), templated epilogue ----------------
template <bool QKV_EPI>
__global__ __launch_bounds__(256) void gemm_k(const unsigned short* __restrict__ A,
                                              const unsigned short* __restrict__ BT,
                                              const float* __restrict__ bias,
                                              void* __restrict__ Cv) {
  constexpr int K = 384;
  constexpr int NT = QKV_EPI ? 9 : 3;
  constexpr int N = NT * 128;
  // sm[buf]: A tile [128][64] at 0, B tile [128][64] at 8192. 2 bufs = 64 KB.
  __shared__ unsigned short sm[2][16384];
  const int bid = blockIdx.x;
  const int swz = (bid & 7) * (NT * 128) + (bid >> 3);  // XCD-aware, bijective
  const int n0 = (swz % NT) * 128;
  const int m0 = (swz / NT) * 128;
  const int tid = threadIdx.x;
  const int lane = tid & 63, wv = tid >> 6;
  const int wr = wv >> 1, wc = wv & 1;
  const int lg = lane >> 4, lr = lane & 15;

  const unsigned short* Ag = A + (size_t)(m0 + wv * 32 + (lane >> 3)) * K + (lane & 7) * 8;
  const unsigned short* Bg = BT + (size_t)(n0 + wv * 32 + (lane >> 3)) * K + (lane & 7) * 8;

  f32x4 acc[4][4];
#pragma unroll
  for (int i = 0; i < 4; ++i)
#pragma unroll
    for (int j = 0; j < 4; ++j) acc[i][j] = zero4();

  auto STAGE = [&](int buf, int k0) {
#pragma unroll
    for (int c2 = 0; c2 < 4; ++c2)
      stage1k(Ag + (size_t)(c2 * 8) * K + k0, &sm[buf][(wv * 32 + c2 * 8) * 64]);
#pragma unroll
    for (int c2 = 0; c2 < 4; ++c2)
      stage1k(Bg + (size_t)(c2 * 8) * K + k0, &sm[buf][8192 + (wv * 32 + c2 * 8) * 64]);
  };
  auto COMPUTE = [&](int buf) {
#pragma unroll
    for (int kk = 0; kk < 64; kk += 32) {
      s16x8 af[4], bf[4];
#pragma unroll
      for (int mt = 0; mt < 4; ++mt)
        af[mt] = *(const s16x8*)&sm[buf][(wr * 64 + 16 * mt + lr) * 64 + kk + 8 * lg];
#pragma unroll
      for (int nt = 0; nt < 4; ++nt)
        bf[nt] = *(const s16x8*)&sm[buf][8192 + (wc * 64 + 16 * nt + lr) * 64 + kk + 8 * lg];
#pragma unroll
      for (int mt = 0; mt < 4; ++mt)
#pragma unroll
        for (int nt = 0; nt < 4; ++nt)
          acc[mt][nt] = mfma32(af[mt], bf[nt], acc[mt][nt]);
    }
  };

  // pipeline: prologue stage(buf0); loop: stage(next), vmcnt(8) [next's 8 stay
  // in flight across the barrier], compute(cur); final drain vmcnt(0).
  STAGE(0, 0);
  int cur = 0;
#pragma unroll 1
  for (int t = 0; t < 5; ++t) {
    STAGE(cur ^ 1, (t + 1) * 64);
    asm volatile("s_waitcnt vmcnt(8)" ::: "memory");
    __builtin_amdgcn_s_barrier();
    asm volatile("" ::: "memory");
    COMPUTE(cur);
    asm volatile("" ::: "memory");
    __builtin_amdgcn_s_barrier();
    cur ^= 1;
  }
  asm volatile("s_waitcnt vmcnt(0)" ::: "memory");
  __builtin_amdgcn_s_barrier();
  asm volatile("" ::: "memory");
  COMPUTE(cur);  // cur == 1: final compute reads sm[1]; epilogue tile uses sm[0]

  const int crow = m0 + wr * 64 + 4 * lg;
  const int ccol = n0 + wc * 64 + lr;
  if constexpr (QKV_EPI) {
    const int sel = n0 / 384;  // block-uniform
    unsigned short* qkv = (unsigned short*)Cv;
    if (sel < 2) {
      // ---- LDS-staged coalesced epilogue (Q/K) ----
      unsigned short* tile = &sm[0][0];  // [128][128] ushort = 32 KB, swizzled
#pragma unroll
      for (int nt = 0; nt < 4; ++nt) {
        const int cc = wc * 64 + 16 * nt + lr;
        const float bv = bias[n0 + cc];
#pragma unroll
        for (int mt = 0; mt < 4; ++mt) {
#pragma unroll
          for (int e = 0; e < 4; ++e) {
            const int r = wr * 64 + 16 * mt + 4 * lg + e;
            tile[r * 128 + (cc ^ ((r & 7) << 3))] = f2bf(acc[mt][nt][e] + bv);
          }
        }
      }
      __syncthreads();
      // read back: wave wv rows [wv*32, wv*32+32), lane covers (l>>2) row pairs,
      // 4 lanes = one dense 64B head-row per (rr,hh) step.
      const int hbase = (n0 - sel * 384) >> 5;  // first of 4 heads in this block
#pragma unroll
      for (int rr = 0; rr < 2; ++rr) {
        const int tr = wv * 32 + rr * 16 + (lane >> 2);
        const int gtok = m0 + tr;
        const int w2 = gtok >> 6, t0r = gtok & 63;
#pragma unroll
        for (int hh = 0; hh < 4; ++hh) {
          const int chunk = hh * 4 + (lane & 3);  // head hh, 16B sub-chunk lane&3
          s16x8 v = *(const s16x8*)&tile[tr * 128 + ((chunk * 8) ^ ((tr & 7) << 3))];
          unsigned short* dst = qkv + (((size_t)w2 * 12 + hbase + hh) * 3 + sel) * 2048 +
                                t0r * 32 + (lane & 3) * 8;
          *(s16x8*)dst = v;
        }
      }
    } else {
      // ---- V: direct transposed store (s16x4 = 4 consecutive tokens) ----
      const int window = crow >> 6;
      const int t0 = crow & 63;
#pragma unroll
      for (int nt = 0; nt < 4; ++nt) {
        const int col = ccol + 16 * nt;
        const int hcol = col - 768;
        const int h = hcol >> 5, d = hcol & 31;
        const float bv = bias[col];
        unsigned short* base = qkv + (((size_t)window * 12 + h) * 3 + 2) * 2048;
#pragma unroll
        for (int mt = 0; mt < 4; ++mt) {
          s16x4 pk;
#pragma unroll
          for (int e = 0; e < 4; ++e) pk[e] = (short)f2bf(acc[mt][nt][e] + bv);
          *(s16x4*)&base[d * 64 + t0 + 16 * mt] = pk;
        }
      }
    }
  } else {
    float* C = (float*)Cv;
#pragma unroll
    for (int mt = 0; mt < 4; ++mt)
#pragma unroll
      for (int nt = 0; nt < 4; ++nt) {
        const int col = ccol + 16 * nt;
        const float bv = bias[col];
#pragma unroll
        for (int e = 0; e < 4; ++e)
          C[(size_t)(crow + 16 * mt + e) * N + col] = acc[mt][nt][e] + bv;
      }
  }
}

// ---------------- attention: one wave per (window, head), no LDS ----------------
__global__ __launch_bounds__(256) void attn_k(const unsigned short* __restrict__ qkv,
                                              const float* __restrict__ biasF,
                                              unsigned short* __restrict__ attnout) {
  const int lane = threadIdx.x & 63;
  const int wv = threadIdx.x >> 6;
  const int wh = blockIdx.x * 4 + wv;  // [0, 24576)
  const int window = wh / 12;
  const int h = wh - window * 12;
  const int lg = lane >> 4, lr = lane & 15;

  const unsigned short* hb = qkv + (size_t)wh * 6144;
  const unsigned short* Qh = hb;
  const unsigned short* Kh = hb + 2048;
  const unsigned short* Vth = hb + 4096;

  s16x8 ka[4], qb[4];
#pragma unroll
  for (int jt = 0; jt < 4; ++jt)
    ka[jt] = *(const s16x8*)&Kh[(jt * 16 + lr) * 32 + 8 * lg];
#pragma unroll
  for (int it = 0; it < 4; ++it)
    qb[it] = *(const s16x8*)&Qh[(it * 16 + lr) * 32 + 8 * lg];

  f32x4 c[4][4];
#pragma unroll
  for (int a = 0; a < 4; ++a)
#pragma unroll
    for (int b2 = 0; b2 < 4; ++b2) c[a][b2] = zero4();

#pragma unroll
  for (int jt = 0; jt < 4; ++jt)
#pragma unroll
    for (int it = 0; it < 4; ++it)
      c[jt][it] = mfma32(ka[jt], qb[it], c[jt][it]);

  const f32x4* bF = (const f32x4*)biasF + ((size_t)h * 16) * 64 + lane;
#pragma unroll
  for (int jt = 0; jt < 4; ++jt)
#pragma unroll
    for (int it = 0; it < 4; ++it)
      c[jt][it] += bF[(jt * 4 + it) * 64];

  s16x4 pb[4][4];
#pragma unroll
  for (int it = 0; it < 4; ++it) {
    float m = -3.0e38f;
#pragma unroll
    for (int jt = 0; jt < 4; ++jt)
#pragma unroll
      for (int e = 0; e < 4; ++e) m = fmaxf(m, c[jt][it][e]);
    m = fmaxf(m, __shfl_xor(m, 16));
    m = fmaxf(m, __shfl_xor(m, 32));
    float s = 0.f;
#pragma unroll
    for (int jt = 0; jt < 4; ++jt)
#pragma unroll
      for (int e = 0; e < 4; ++e) {
        float p = __expf(c[jt][it][e] - m);
        c[jt][it][e] = p;
        s += p;
      }
    s += __shfl_xor(s, 16);
    s += __shfl_xor(s, 32);
    const float inv = 1.f / s;
#pragma unroll
    for (int jt = 0; jt < 4; ++jt) {
      s16x4 pk;
#pragma unroll
      for (int e = 0; e < 4; ++e) pk[e] = (short)f2bf(c[jt][it][e] * inv);
      pb[jt][it] = pk;
    }
  }

  f32x4 o[2][4];
#pragma unroll
  for (int a = 0; a < 2; ++a)
#pragma unroll
    for (int b2 = 0; b2 < 4; ++b2) o[a][b2] = zero4();

#pragma unroll
  for (int jt = 0; jt < 4; ++jt) {
    s16x4 va[2];
#pragma unroll
    for (int dt = 0; dt < 2; ++dt)
      va[dt] = *(const s16x4*)&Vth[(dt * 16 + lr) * 64 + jt * 16 + 4 * lg];
#pragma unroll
    for (int dt = 0; dt < 2; ++dt)
#pragma unroll
      for (int it = 0; it < 4; ++it)
        o[dt][it] = mfma16(va[dt], pb[jt][it], o[dt][it]);
  }

  unsigned short* ob = attnout + (size_t)window * 64 * 384;
#pragma unroll
  for (int dt = 0; dt < 2; ++dt)
#pragma unroll
    for (int it = 0; it < 4; ++it) {
      s16x4 pk;
#pragma unroll
      for (int e = 0; e < 4; ++e) pk[e] = (short)f2bf(o[dt][it][e]);
      *(s16x4*)&ob[(size_t)(it * 16 + lr) * 384 + h * 32 + dt * 16 + 4 * lg] = pk;
    }
}

extern "C" void kernel_launch(void* const* d_in, const int* in_sizes, int n_in,
                              void* d_out, int out_size, void* d_ws, size_t ws_size,
                              hipStream_t stream) {
  const float* x = (const float*)d_in[0];
  const float* Wqkv = (const float*)d_in[1];
  const float* bqkv = (const float*)d_in[2];
  const float* Wm = (const float*)d_in[3];
  const float* bm = (const float*)d_in[4];
  const float* rel = (const float*)d_in[5];

  const size_t M = 131072;  // B*G*P
  char* ws = (char*)d_ws;
  size_t off = 0;
  unsigned short* qkv = (unsigned short*)(ws + off);   off += M * 1152 * 2;  // 302 MB
  unsigned short* xb = (unsigned short*)(ws + off);    off += M * 384 * 2;   // 100 MB (reused as attnout)
  unsigned short* WqkvT = (unsigned short*)(ws + off); off += 1152 * 384 * 2;
  unsigned short* WmT = (unsigned short*)(ws + off);   off += 384 * 384 * 2;
  float* biasF = (float*)(ws + off);                   off += 12 * 16 * 64 * 4 * 4;
  float* bqkvs = (float*)(ws + off);                   off += 1152 * 4;
  unsigned short* attnout = xb;  // xb is dead after gemm1

  if (ws_size < off) {
    fill_val<<<(out_size + 255) / 256, 256, 0, stream>>>((float*)d_out, out_size, 12345.0f);
    return;
  }

  prep_wqkvT<<<(1152 * 384 + 255) / 256, 256, 0, stream>>>(Wqkv, WqkvT);
  prep_wmT<<<(384 * 384 + 255) / 256, 256, 0, stream>>>(Wm, WmT);
  prep_bqkv<<<5, 256, 0, stream>>>(bqkv, bqkvs);
  prep_biasF<<<48, 256, 0, stream>>>(rel, biasF);
  conv_bf16<<<2048, 256, 0, stream>>>(x, xb);

  gemm_k<true><<<9216, 256, 0, stream>>>(xb, WqkvT, bqkvs, qkv);
  attn_k<<<6144, 256, 0, stream>>>(qkv, biasF, attnout);
  gemm_k<false><<<3072, 256, 0, stream>>>(attnout, WmT, bm, d_out);
}

// Round 7
// 468.202 us; speedup vs baseline: 1.3322x; 1.0371x over previous
//
#include <hip/hip_runtime.h>
#include <stdint.h>

// Round 7: R6's T2 swizzle kept (algebra re-verified, matches m201 pattern), but
// the fragile counted-vmcnt(8) pipeline replaced with the order-independent
// 2-phase recipe: STAGE(next); COMPUTE(cur); __syncthreads() — one barrier per
// tile, vmcnt(0) inside syncthreads drains regardless of compiler load order.
// Loads still overlap the full COMPUTE phase. No inline asm in the loop.

typedef __attribute__((ext_vector_type(4))) float f32x4;
typedef __attribute__((ext_vector_type(4))) short s16x4;
typedef __attribute__((ext_vector_type(8))) short s16x8;

#define DEVI static __device__ __forceinline__

DEVI unsigned short f2bf(float f) {
  union { float f; uint32_t u; } v; v.f = f;
  return (unsigned short)((v.u + 0x7FFFu + ((v.u >> 16) & 1u)) >> 16);
}

DEVI f32x4 zero4() { f32x4 z; z[0] = 0.f; z[1] = 0.f; z[2] = 0.f; z[3] = 0.f; return z; }

#if defined(__has_builtin)
#if __has_builtin(__builtin_amdgcn_mfma_f32_16x16x16bf16_1k)
#define MFMA16_BUILTIN 1
#endif
#if __has_builtin(__builtin_amdgcn_global_load_lds)
#define HAS_GLLDS 1
#endif
#endif

DEVI f32x4 mfma16(s16x4 a, s16x4 b, f32x4 c) {
#ifdef MFMA16_BUILTIN
  return __builtin_amdgcn_mfma_f32_16x16x16bf16_1k(a, b, c, 0, 0, 0);
#else
  asm volatile("v_mfma_f32_16x16x16_bf16 %0, %1, %2, %0" : "+v"(c) : "v"(a), "v"(b));
  return c;
#endif
}

DEVI f32x4 mfma32(s16x8 a, s16x8 b, f32x4 c) {
  return __builtin_amdgcn_mfma_f32_16x16x32_bf16(a, b, c, 0, 0, 0);
}

DEVI void stage1k(const unsigned short* g_lane, unsigned short* lds_base) {
#ifdef HAS_GLLDS
  __builtin_amdgcn_global_load_lds(
      (const __attribute__((address_space(1))) unsigned int*)g_lane,
      (__attribute__((address_space(3))) unsigned int*)lds_base, 16, 0, 0);
#else
  *(s16x8*)(lds_base + (threadIdx.x & 63) * 8) = *(const s16x8*)g_lane;
#endif
}

// ---------------- prep kernels ----------------
__global__ void prep_wqkvT(const float* __restrict__ W, unsigned short* __restrict__ WT) {
  int t = blockIdx.x * 256 + threadIdx.x;
  if (t >= 1152 * 384) return;
  int n = t / 384, k = t - n * 384;
  float s = (n < 384) ? 0.17677669529663687f : 1.0f;  // HEAD_DIM^-0.5 folded into Wq
  WT[t] = f2bf(W[(size_t)k * 1152 + n] * s);
}

__global__ void prep_wmT(const float* __restrict__ W, unsigned short* __restrict__ WT) {
  int t = blockIdx.x * 256 + threadIdx.x;
  if (t >= 384 * 384) return;
  int n = t / 384, k = t - n * 384;
  WT[t] = f2bf(W[(size_t)k * 384 + n]);
}

__global__ void prep_bqkv(const float* __restrict__ b, float* __restrict__ bs) {
  int t = blockIdx.x * 256 + threadIdx.x;
  if (t >= 1152) return;
  bs[t] = b[t] * ((t < 384) ? 0.17677669529663687f : 1.0f);
}

// biasF: per-lane fragment order. biasF[((h*16 + jt*4 + it)*64 + lane)*4 + e]
__global__ void prep_biasF(const float* __restrict__ rel, float* __restrict__ biasF) {
  int t = blockIdx.x * 256 + threadIdx.x;  // 12*16*64 = 12288
  if (t >= 12288) return;
  int h = t >> 10;
  int r = (t >> 6) & 15;
  int lane = t & 63;
  int jt = r >> 2, it = r & 3;
  int lg = lane >> 4, lr = lane & 15;
  int i = it * 16 + lr;
#pragma unroll
  for (int e = 0; e < 4; ++e) {
    int j = jt * 16 + lg * 4 + e;
    int idx = ((i >> 3) - (j >> 3) + 7) * 15 + ((i & 7) - (j & 7) + 7);
    biasF[t * 4 + e] = rel[idx * 12 + h];
  }
}

__global__ void fill_val(float* o, int n, float v) {
  int t = blockIdx.x * 256 + threadIdx.x;
  if (t < n) o[t] = v;
}

// ---------------- x fp32 -> bf16 ----------------
__global__ __launch_bounds__(256) void conv_bf16(const float* __restrict__ x,
                                                 unsigned short* __restrict__ xb) {
  const size_t nchunk = 131072UL * 384 / 8;
  const size_t stride = (size_t)gridDim.x * blockDim.x;
  for (size_t i = (size_t)blockIdx.x * blockDim.x + threadIdx.x; i < nchunk; i += stride) {
    f32x4 a = *(const f32x4*)(x + i * 8);
    f32x4 b = *(const f32x4*)(x + i * 8 + 4);
    s16x8 p;
    p[0] = (short)f2bf(a[0]); p[1] = (short)f2bf(a[1]);
    p[2] = (short)f2bf(a[2]); p[3] = (short)f2bf(a[3]);
    p[4] = (short)f2bf(b[0]); p[5] = (short)f2bf(b[1]);
    p[6] = (short)f2bf(b[2]); p[7] = (short)f2bf(b[3]);
    *(s16x8*)(xb + i * 8) = p;
  }
}

// ---------------- GEMM (2-phase dbuf + T2 swizzle) ----------------
template <bool QKV_EPI>
__global__ __launch_bounds__(256) void gemm_k(const unsigned short* __restrict__ A,
                                              const unsigned short* __restrict__ BT,
                                              const float* __restrict__ bias,
                                              void* __restrict__ Cv) {
  constexpr int K = 384;
  constexpr int NT = QKV_EPI ? 9 : 3;
  constexpr int N = NT * 128;
  // sm[buf]: A tile [128][64] at 0, B tile [128][64] at 8192. 2 bufs = 64 KB.
  __shared__ unsigned short sm[2][16384];
  const int bid = blockIdx.x;
  const int swz = (bid & 7) * (NT * 128) + (bid >> 3);  // XCD-aware, bijective
  const int n0 = (swz % NT) * 128;
  const int m0 = (swz / NT) * 128;
  const int tid = threadIdx.x;
  const int lane = tid & 63, wv = tid >> 6;
  const int wr = wv >> 1, wc = wv & 1;
  const int lg = lane >> 4, lr = lane & 15;

  // T2 swizzle, write side: LDS(r, ce) holds data[r][ce ^ ((r&7)<<3)]; within a
  // 1KiB stage call lane l sits at r=l>>3, ce=(l&7)*8, so its GLOBAL col is
  // 8*((l&7) ^ (l>>3)). LDS dest stays linear (rule #21).
  const int scol = ((lane & 7) ^ (lane >> 3)) * 8;
  const unsigned short* Ag = A + (size_t)(m0 + wv * 32 + (lane >> 3)) * K + scol;
  const unsigned short* Bg = BT + (size_t)(n0 + wv * 32 + (lane >> 3)) * K + scol;

  f32x4 acc[4][4];
#pragma unroll
  for (int i = 0; i < 4; ++i)
#pragma unroll
    for (int j = 0; j < 4; ++j) acc[i][j] = zero4();

  auto STAGE = [&](int buf, int k0) {
#pragma unroll
    for (int c2 = 0; c2 < 4; ++c2)
      stage1k(Ag + (size_t)(c2 * 8) * K + k0, &sm[buf][(wv * 32 + c2 * 8) * 64]);
#pragma unroll
    for (int c2 = 0; c2 < 4; ++c2)
      stage1k(Bg + (size_t)(c2 * 8) * K + k0, &sm[buf][8192 + (wv * 32 + c2 * 8) * 64]);
  };
  // T2 swizzle, read side: same involution on the column bits.
  const int sa = (lr & 7) << 3;
  auto COMPUTE = [&](int buf) {
#pragma unroll
    for (int kk = 0; kk < 64; kk += 32) {
      s16x8 af[4], bf[4];
#pragma unroll
      for (int mt = 0; mt < 4; ++mt)
        af[mt] = *(const s16x8*)&sm[buf][(wr * 64 + 16 * mt + lr) * 64 + ((kk + 8 * lg) ^ sa)];
#pragma unroll
      for (int nt = 0; nt < 4; ++nt)
        bf[nt] = *(const s16x8*)&sm[buf][8192 + (wc * 64 + 16 * nt + lr) * 64 + ((kk + 8 * lg) ^ sa)];
#pragma unroll
      for (int mt = 0; mt < 4; ++mt)
#pragma unroll
        for (int nt = 0; nt < 4; ++nt)
          acc[mt][nt] = mfma32(af[mt], bf[nt], acc[mt][nt]);
    }
  };

  // 2-phase pipeline (order-independent sync): issue next-tile loads, compute
  // current tile, then __syncthreads() (vmcnt(0)+barrier) retires the loads
  // that were in flight during the whole COMPUTE.
  STAGE(0, 0);
  __syncthreads();
  int cur = 0;
#pragma unroll 1
  for (int t = 0; t < 5; ++t) {
    STAGE(cur ^ 1, (t + 1) * 64);
    COMPUTE(cur);
    __syncthreads();
    cur ^= 1;
  }
  COMPUTE(cur);  // cur == 1: final compute reads sm[1]; epilogue tile uses sm[0]

  const int crow = m0 + wr * 64 + 4 * lg;
  const int ccol = n0 + wc * 64 + lr;
  if constexpr (QKV_EPI) {
    const int sel = n0 / 384;  // block-uniform
    unsigned short* qkv = (unsigned short*)Cv;
    if (sel < 2) {
      // ---- LDS-staged coalesced epilogue (Q/K) ----
      unsigned short* tile = &sm[0][0];  // [128][128] ushort = 32 KB, swizzled
#pragma unroll
      for (int nt = 0; nt < 4; ++nt) {
        const int cc = wc * 64 + 16 * nt + lr;
        const float bv = bias[n0 + cc];
#pragma unroll
        for (int mt = 0; mt < 4; ++mt) {
#pragma unroll
          for (int e = 0; e < 4; ++e) {
            const int r = wr * 64 + 16 * mt + 4 * lg + e;
            tile[r * 128 + (cc ^ ((r & 7) << 3))] = f2bf(acc[mt][nt][e] + bv);
          }
        }
      }
      __syncthreads();
      // read back: wave wv rows [wv*32, wv*32+32), 4 lanes = one dense 64B head-row.
      const int hbase = (n0 - sel * 384) >> 5;  // first of 4 heads in this block
#pragma unroll
      for (int rr = 0; rr < 2; ++rr) {
        const int tr = wv * 32 + rr * 16 + (lane >> 2);
        const int gtok = m0 + tr;
        const int w2 = gtok >> 6, t0r = gtok & 63;
#pragma unroll
        for (int hh = 0; hh < 4; ++hh) {
          const int chunk = hh * 4 + (lane & 3);  // head hh, 16B sub-chunk lane&3
          s16x8 v = *(const s16x8*)&tile[tr * 128 + ((chunk * 8) ^ ((tr & 7) << 3))];
          unsigned short* dst = qkv + (((size_t)w2 * 12 + hbase + hh) * 3 + sel) * 2048 +
                                t0r * 32 + (lane & 3) * 8;
          *(s16x8*)dst = v;
        }
      }
    } else {
      // ---- V: direct transposed store (s16x4 = 4 consecutive tokens) ----
      const int window = crow >> 6;
      const int t0 = crow & 63;
#pragma unroll
      for (int nt = 0; nt < 4; ++nt) {
        const int col = ccol + 16 * nt;
        const int hcol = col - 768;
        const int h = hcol >> 5, d = hcol & 31;
        const float bv = bias[col];
        unsigned short* base = qkv + (((size_t)window * 12 + h) * 3 + 2) * 2048;
#pragma unroll
        for (int mt = 0; mt < 4; ++mt) {
          s16x4 pk;
#pragma unroll
          for (int e = 0; e < 4; ++e) pk[e] = (short)f2bf(acc[mt][nt][e] + bv);
          *(s16x4*)&base[d * 64 + t0 + 16 * mt] = pk;
        }
      }
    }
  } else {
    float* C = (float*)Cv;
#pragma unroll
    for (int mt = 0; mt < 4; ++mt)
#pragma unroll
      for (int nt = 0; nt < 4; ++nt) {
        const int col = ccol + 16 * nt;
        const float bv = bias[col];
#pragma unroll
        for (int e = 0; e < 4; ++e)
          C[(size_t)(crow + 16 * mt + e) * N + col] = acc[mt][nt][e] + bv;
      }
  }
}

// ---------------- attention: one wave per (window, head), no LDS ----------------
__global__ __launch_bounds__(256) void attn_k(const unsigned short* __restrict__ qkv,
                                              const float* __restrict__ biasF,
                                              unsigned short* __restrict__ attnout) {
  const int lane = threadIdx.x & 63;
  const int wv = threadIdx.x >> 6;
  const int wh = blockIdx.x * 4 + wv;  // [0, 24576)
  const int window = wh / 12;
  const int h = wh - window * 12;
  const int lg = lane >> 4, lr = lane & 15;

  const unsigned short* hb = qkv + (size_t)wh * 6144;
  const unsigned short* Qh = hb;
  const unsigned short* Kh = hb + 2048;
  const unsigned short* Vth = hb + 4096;

  s16x8 ka[4], qb[4];
#pragma unroll
  for (int jt = 0; jt < 4; ++jt)
    ka[jt] = *(const s16x8*)&Kh[(jt * 16 + lr) * 32 + 8 * lg];
#pragma unroll
  for (int it = 0; it < 4; ++it)
    qb[it] = *(const s16x8*)&Qh[(it * 16 + lr) * 32 + 8 * lg];

  f32x4 c[4][4];
#pragma unroll
  for (int a = 0; a < 4; ++a)
#pragma unroll
    for (int b2 = 0; b2 < 4; ++b2) c[a][b2] = zero4();

#pragma unroll
  for (int jt = 0; jt < 4; ++jt)
#pragma unroll
    for (int it = 0; it < 4; ++it)
      c[jt][it] = mfma32(ka[jt], qb[it], c[jt][it]);

  const f32x4* bF = (const f32x4*)biasF + ((size_t)h * 16) * 64 + lane;
#pragma unroll
  for (int jt = 0; jt < 4; ++jt)
#pragma unroll
    for (int it = 0; it < 4; ++it)
      c[jt][it] += bF[(jt * 4 + it) * 64];

  s16x4 pb[4][4];
#pragma unroll
  for (int it = 0; it < 4; ++it) {
    float m = -3.0e38f;
#pragma unroll
    for (int jt = 0; jt < 4; ++jt)
#pragma unroll
      for (int e = 0; e < 4; ++e) m = fmaxf(m, c[jt][it][e]);
    m = fmaxf(m, __shfl_xor(m, 16));
    m = fmaxf(m, __shfl_xor(m, 32));
    float s = 0.f;
#pragma unroll
    for (int jt = 0; jt < 4; ++jt)
#pragma unroll
      for (int e = 0; e < 4; ++e) {
        float p = __expf(c[jt][it][e] - m);
        c[jt][it][e] = p;
        s += p;
      }
    s += __shfl_xor(s, 16);
    s += __shfl_xor(s, 32);
    const float inv = 1.f / s;
#pragma unroll
    for (int jt = 0; jt < 4; ++jt) {
      s16x4 pk;
#pragma unroll
      for (int e = 0; e < 4; ++e) pk[e] = (short)f2bf(c[jt][it][e] * inv);
      pb[jt][it] = pk;
    }
  }

  f32x4 o[2][4];
#pragma unroll
  for (int a = 0; a < 2; ++a)
#pragma unroll
    for (int b2 = 0; b2 < 4; ++b2) o[a][b2] = zero4();

#pragma unroll
  for (int jt = 0; jt < 4; ++jt) {
    s16x4 va[2];
#pragma unroll
    for (int dt = 0; dt < 2; ++dt)
      va[dt] = *(const s16x4*)&Vth[(dt * 16 + lr) * 64 + jt * 16 + 4 * lg];
#pragma unroll
    for (int dt = 0; dt < 2; ++dt)
#pragma unroll
      for (int it = 0; it < 4; ++it)
        o[dt][it] = mfma16(va[dt], pb[jt][it], o[dt][it]);
  }

  unsigned short* ob = attnout + (size_t)window * 64 * 384;
#pragma unroll
  for (int dt = 0; dt < 2; ++dt)
#pragma unroll
    for (int it = 0; it < 4; ++it) {
      s16x4 pk;
#pragma unroll
      for (int e = 0; e < 4; ++e) pk[e] = (short)f2bf(o[dt][it][e]);
      *(s16x4*)&ob[(size_t)(it * 16 + lr) * 384 + h * 32 + dt * 16 + 4 * lg] = pk;
    }
}

extern "C" void kernel_launch(void* const* d_in, const int* in_sizes, int n_in,
                              void* d_out, int out_size, void* d_ws, size_t ws_size,
                              hipStream_t stream) {
  const float* x = (const float*)d_in[0];
  const float* Wqkv = (const float*)d_in[1];
  const float* bqkv = (const float*)d_in[2];
  const float* Wm = (const float*)d_in[3];
  const float* bm = (const float*)d_in[4];
  const float* rel = (const float*)d_in[5];

  const size_t M = 131072;  // B*G*P
  char* ws = (char*)d_ws;
  size_t off = 0;
  unsigned short* qkv = (unsigned short*)(ws + off);   off += M * 1152 * 2;  // 302 MB
  unsigned short* xb = (unsigned short*)(ws + off);    off += M * 384 * 2;   // 100 MB (reused as attnout)
  unsigned short* WqkvT = (unsigned short*)(ws + off); off += 1152 * 384 * 2;
  unsigned short* WmT = (unsigned short*)(ws + off);   off += 384 * 384 * 2;
  float* biasF = (float*)(ws + off);                   off += 12 * 16 * 64 * 4 * 4;
  float* bqkvs = (float*)(ws + off);                   off += 1152 * 4;
  unsigned short* attnout = xb;  // xb is dead after gemm1

  if (ws_size < off) {
    fill_val<<<(out_size + 255) / 256, 256, 0, stream>>>((float*)d_out, out_size, 12345.0f);
    return;
  }

  prep_wqkvT<<<(1152 * 384 + 255) / 256, 256, 0, stream>>>(Wqkv, WqkvT);
  prep_wmT<<<(384 * 384 + 255) / 256, 256, 0, stream>>>(Wm, WmT);
  prep_bqkv<<<5, 256, 0, stream>>>(bqkv, bqkvs);
  prep_biasF<<<48, 256, 0, stream>>>(rel, biasF);
  conv_bf16<<<2048, 256, 0, stream>>>(x, xb);

  gemm_k<true><<<9216, 256, 0, stream>>>(xb, WqkvT, bqkvs, qkv);
  attn_k<<<6144, 256, 0, stream>>>(qkv, biasF, attnout);
  gemm_k<false><<<3072, 256, 0, stream>>>(attnout, WmT, bm, d_out);
}

// Round 8
// 461.920 us; speedup vs baseline: 1.3503x; 1.0136x over previous
//
#include <hip/hip_runtime.h>
#include <stdint.h>

// Round 8: 8-wave (512-thread) GEMM blocks, same 128x128xBK64 tile + 64KB dbuf
// LDS -> still 2 blocks/CU but 16 waves/CU (2x TLP). Wave grid 2x4, each wave
// 64x32 out. T2 swizzle + 2-phase syncthreads pipeline (R7, verified) kept.

typedef __attribute__((ext_vector_type(4))) float f32x4;
typedef __attribute__((ext_vector_type(4))) short s16x4;
typedef __attribute__((ext_vector_type(8))) short s16x8;

#define DEVI static __device__ __forceinline__

DEVI unsigned short f2bf(float f) {
  union { float f; uint32_t u; } v; v.f = f;
  return (unsigned short)((v.u + 0x7FFFu + ((v.u >> 16) & 1u)) >> 16);
}

DEVI f32x4 zero4() { f32x4 z; z[0] = 0.f; z[1] = 0.f; z[2] = 0.f; z[3] = 0.f; return z; }

#if defined(__has_builtin)
#if __has_builtin(__builtin_amdgcn_mfma_f32_16x16x16bf16_1k)
#define MFMA16_BUILTIN 1
#endif
#if __has_builtin(__builtin_amdgcn_global_load_lds)
#define HAS_GLLDS 1
#endif
#endif

DEVI f32x4 mfma16(s16x4 a, s16x4 b, f32x4 c) {
#ifdef MFMA16_BUILTIN
  return __builtin_amdgcn_mfma_f32_16x16x16bf16_1k(a, b, c, 0, 0, 0);
#else
  asm volatile("v_mfma_f32_16x16x16_bf16 %0, %1, %2, %0" : "+v"(c) : "v"(a), "v"(b));
  return c;
#endif
}

DEVI f32x4 mfma32(s16x8 a, s16x8 b, f32x4 c) {
  return __builtin_amdgcn_mfma_f32_16x16x32_bf16(a, b, c, 0, 0, 0);
}

DEVI void stage1k(const unsigned short* g_lane, unsigned short* lds_base) {
#ifdef HAS_GLLDS
  __builtin_amdgcn_global_load_lds(
      (const __attribute__((address_space(1))) unsigned int*)g_lane,
      (__attribute__((address_space(3))) unsigned int*)lds_base, 16, 0, 0);
#else
  *(s16x8*)(lds_base + (threadIdx.x & 63) * 8) = *(const s16x8*)g_lane;
#endif
}

// ---------------- prep kernels ----------------
__global__ void prep_wqkvT(const float* __restrict__ W, unsigned short* __restrict__ WT) {
  int t = blockIdx.x * 256 + threadIdx.x;
  if (t >= 1152 * 384) return;
  int n = t / 384, k = t - n * 384;
  float s = (n < 384) ? 0.17677669529663687f : 1.0f;  // HEAD_DIM^-0.5 folded into Wq
  WT[t] = f2bf(W[(size_t)k * 1152 + n] * s);
}

__global__ void prep_wmT(const float* __restrict__ W, unsigned short* __restrict__ WT) {
  int t = blockIdx.x * 256 + threadIdx.x;
  if (t >= 384 * 384) return;
  int n = t / 384, k = t - n * 384;
  WT[t] = f2bf(W[(size_t)k * 384 + n]);
}

__global__ void prep_bqkv(const float* __restrict__ b, float* __restrict__ bs) {
  int t = blockIdx.x * 256 + threadIdx.x;
  if (t >= 1152) return;
  bs[t] = b[t] * ((t < 384) ? 0.17677669529663687f : 1.0f);
}

// biasF: per-lane fragment order. biasF[((h*16 + jt*4 + it)*64 + lane)*4 + e]
__global__ void prep_biasF(const float* __restrict__ rel, float* __restrict__ biasF) {
  int t = blockIdx.x * 256 + threadIdx.x;  // 12*16*64 = 12288
  if (t >= 12288) return;
  int h = t >> 10;
  int r = (t >> 6) & 15;
  int lane = t & 63;
  int jt = r >> 2, it = r & 3;
  int lg = lane >> 4, lr = lane & 15;
  int i = it * 16 + lr;
#pragma unroll
  for (int e = 0; e < 4; ++e) {
    int j = jt * 16 + lg * 4 + e;
    int idx = ((i >> 3) - (j >> 3) + 7) * 15 + ((i & 7) - (j & 7) + 7);
    biasF[t * 4 + e] = rel[idx * 12 + h];
  }
}

__global__ void fill_val(float* o, int n, float v) {
  int t = blockIdx.x * 256 + threadIdx.x;
  if (t < n) o[t] = v;
}

// ---------------- x fp32 -> bf16 ----------------
__global__ __launch_bounds__(256) void conv_bf16(const float* __restrict__ x,
                                                 unsigned short* __restrict__ xb) {
  const size_t nchunk = 131072UL * 384 / 8;
  const size_t stride = (size_t)gridDim.x * blockDim.x;
  for (size_t i = (size_t)blockIdx.x * blockDim.x + threadIdx.x; i < nchunk; i += stride) {
    f32x4 a = *(const f32x4*)(x + i * 8);
    f32x4 b = *(const f32x4*)(x + i * 8 + 4);
    s16x8 p;
    p[0] = (short)f2bf(a[0]); p[1] = (short)f2bf(a[1]);
    p[2] = (short)f2bf(a[2]); p[3] = (short)f2bf(a[3]);
    p[4] = (short)f2bf(b[0]); p[5] = (short)f2bf(b[1]);
    p[6] = (short)f2bf(b[2]); p[7] = (short)f2bf(b[3]);
    *(s16x8*)(xb + i * 8) = p;
  }
}

// ---------------- GEMM (8 waves, 2-phase dbuf + T2 swizzle) ----------------
template <bool QKV_EPI>
__global__ __launch_bounds__(512, 4) void gemm_k(const unsigned short* __restrict__ A,
                                                 const unsigned short* __restrict__ BT,
                                                 const float* __restrict__ bias,
                                                 void* __restrict__ Cv) {
  constexpr int K = 384;
  constexpr int NT = QKV_EPI ? 9 : 3;
  constexpr int N = NT * 128;
  // sm[buf]: A tile [128][64] at ushort 0, B tile [128][64] at ushort 8192.
  __shared__ unsigned short sm[2][16384];
  const int bid = blockIdx.x;
  const int swz = (bid & 7) * (NT * 128) + (bid >> 3);  // XCD-aware, bijective
  const int n0 = (swz % NT) * 128;
  const int m0 = (swz / NT) * 128;
  const int tid = threadIdx.x;
  const int lane = tid & 63, wv = tid >> 6;       // wv 0..7
  const int wr = wv >> 2, wc = wv & 3;            // wave grid 2x4: 64 rows x 32 cols
  const int lg = lane >> 4, lr = lane & 15;

  // T2 swizzle write side: lane l covers row l>>3, LDS col-slot 8*(l&7);
  // its GLOBAL col is 8*((l&7) ^ (l>>3)). LDS dest linear (rule #21).
  const int scol = ((lane & 7) ^ (lane >> 3)) * 8;
  const unsigned short* Ag = A + (size_t)(m0 + wv * 16 + (lane >> 3)) * K + scol;
  const unsigned short* Bg = BT + (size_t)(n0 + wv * 16 + (lane >> 3)) * K + scol;

  f32x4 acc[4][2];
#pragma unroll
  for (int i = 0; i < 4; ++i)
#pragma unroll
    for (int j = 0; j < 2; ++j) acc[i][j] = zero4();

  auto STAGE = [&](int buf, int k0) {
#pragma unroll
    for (int c2 = 0; c2 < 2; ++c2)
      stage1k(Ag + (size_t)(c2 * 8) * K + k0, &sm[buf][(wv * 16 + c2 * 8) * 64]);
#pragma unroll
    for (int c2 = 0; c2 < 2; ++c2)
      stage1k(Bg + (size_t)(c2 * 8) * K + k0, &sm[buf][8192 + (wv * 16 + c2 * 8) * 64]);
  };
  // T2 read side: same involution on column bits.
  const int sa = (lr & 7) << 3;
  auto COMPUTE = [&](int buf) {
#pragma unroll
    for (int kk = 0; kk < 64; kk += 32) {
      s16x8 af[4], bf[2];
#pragma unroll
      for (int mt = 0; mt < 4; ++mt)
        af[mt] = *(const s16x8*)&sm[buf][(wr * 64 + 16 * mt + lr) * 64 + ((kk + 8 * lg) ^ sa)];
#pragma unroll
      for (int nt = 0; nt < 2; ++nt)
        bf[nt] = *(const s16x8*)&sm[buf][8192 + (wc * 32 + 16 * nt + lr) * 64 + ((kk + 8 * lg) ^ sa)];
#pragma unroll
      for (int mt = 0; mt < 4; ++mt)
#pragma unroll
        for (int nt = 0; nt < 2; ++nt)
          acc[mt][nt] = mfma32(af[mt], bf[nt], acc[mt][nt]);
    }
  };

  // 2-phase pipeline: STAGE(next); COMPUTE(cur); __syncthreads() (drains vmcnt
  // regardless of compiler load ordering — the R7-verified structure).
  STAGE(0, 0);
  __syncthreads();
  int cur = 0;
#pragma unroll 1
  for (int t = 0; t < 5; ++t) {
    STAGE(cur ^ 1, (t + 1) * 64);
    COMPUTE(cur);
    __syncthreads();
    cur ^= 1;
  }
  COMPUTE(cur);  // cur == 1: final compute reads sm[1]; epilogue tile uses sm[0]

  const int crow = m0 + wr * 64 + 4 * lg;
  const int ccol = n0 + wc * 32 + lr;
  if constexpr (QKV_EPI) {
    const int sel = n0 / 384;  // block-uniform
    unsigned short* qkv = (unsigned short*)Cv;
    if (sel < 2) {
      // ---- LDS-staged coalesced epilogue (Q/K), tile [128][128] in sm[0] ----
      unsigned short* tile = &sm[0][0];
#pragma unroll
      for (int nt = 0; nt < 2; ++nt) {
        const int cc = wc * 32 + 16 * nt + lr;
        const float bv = bias[n0 + cc];
#pragma unroll
        for (int mt = 0; mt < 4; ++mt) {
#pragma unroll
          for (int e = 0; e < 4; ++e) {
            const int r = wr * 64 + 16 * mt + 4 * lg + e;
            tile[r * 128 + (cc ^ ((r & 7) << 3))] = f2bf(acc[mt][nt][e] + bv);
          }
        }
      }
      __syncthreads();
      // readback: wave wv rows [wv*16, +16), lane>>2 = row, lane&3 = 16B chunk;
      // 4 lanes produce one dense 64B head-row; hh walks the 4 heads.
      const int hbase = (n0 - sel * 384) >> 5;
      const int tr = wv * 16 + (lane >> 2);
      const int gtok = m0 + tr;
      const int w2 = gtok >> 6, t0r = gtok & 63;
#pragma unroll
      for (int hh = 0; hh < 4; ++hh) {
        const int chunk = hh * 4 + (lane & 3);
        s16x8 v = *(const s16x8*)&tile[tr * 128 + ((chunk * 8) ^ ((tr & 7) << 3))];
        unsigned short* dst = qkv + (((size_t)w2 * 12 + hbase + hh) * 3 + sel) * 2048 +
                              t0r * 32 + (lane & 3) * 8;
        *(s16x8*)dst = v;
      }
    } else {
      // ---- V: direct transposed store (s16x4 = 4 consecutive tokens) ----
      const int window = crow >> 6;
      const int t0 = crow & 63;  // 4*lg
#pragma unroll
      for (int nt = 0; nt < 2; ++nt) {
        const int col = ccol + 16 * nt;
        const int hcol = col - 768;
        const int h = hcol >> 5, d = hcol & 31;
        const float bv = bias[col];
        unsigned short* base = qkv + (((size_t)window * 12 + h) * 3 + 2) * 2048;
#pragma unroll
        for (int mt = 0; mt < 4; ++mt) {
          s16x4 pk;
#pragma unroll
          for (int e = 0; e < 4; ++e) pk[e] = (short)f2bf(acc[mt][nt][e] + bv);
          *(s16x4*)&base[d * 64 + t0 + 16 * mt] = pk;
        }
      }
    }
  } else {
    float* C = (float*)Cv;
#pragma unroll
    for (int mt = 0; mt < 4; ++mt)
#pragma unroll
      for (int nt = 0; nt < 2; ++nt) {
        const int col = ccol + 16 * nt;
        const float bv = bias[col];
#pragma unroll
        for (int e = 0; e < 4; ++e)
          C[(size_t)(crow + 16 * mt + e) * N + col] = acc[mt][nt][e] + bv;
      }
  }
}

// ---------------- attention: one wave per (window, head), no LDS ----------------
__global__ __launch_bounds__(256) void attn_k(const unsigned short* __restrict__ qkv,
                                              const float* __restrict__ biasF,
                                              unsigned short* __restrict__ attnout) {
  const int lane = threadIdx.x & 63;
  const int wv = threadIdx.x >> 6;
  const int wh = blockIdx.x * 4 + wv;  // [0, 24576)
  const int window = wh / 12;
  const int h = wh - window * 12;
  const int lg = lane >> 4, lr = lane & 15;

  const unsigned short* hb = qkv + (size_t)wh * 6144;
  const unsigned short* Qh = hb;
  const unsigned short* Kh = hb + 2048;
  const unsigned short* Vth = hb + 4096;

  s16x8 ka[4], qb[4];
#pragma unroll
  for (int jt = 0; jt < 4; ++jt)
    ka[jt] = *(const s16x8*)&Kh[(jt * 16 + lr) * 32 + 8 * lg];
#pragma unroll
  for (int it = 0; it < 4; ++it)
    qb[it] = *(const s16x8*)&Qh[(it * 16 + lr) * 32 + 8 * lg];

  f32x4 c[4][4];
#pragma unroll
  for (int a = 0; a < 4; ++a)
#pragma unroll
    for (int b2 = 0; b2 < 4; ++b2) c[a][b2] = zero4();

#pragma unroll
  for (int jt = 0; jt < 4; ++jt)
#pragma unroll
    for (int it = 0; it < 4; ++it)
      c[jt][it] = mfma32(ka[jt], qb[it], c[jt][it]);

  const f32x4* bF = (const f32x4*)biasF + ((size_t)h * 16) * 64 + lane;
#pragma unroll
  for (int jt = 0; jt < 4; ++jt)
#pragma unroll
    for (int it = 0; it < 4; ++it)
      c[jt][it] += bF[(jt * 4 + it) * 64];

  s16x4 pb[4][4];
#pragma unroll
  for (int it = 0; it < 4; ++it) {
    float m = -3.0e38f;
#pragma unroll
    for (int jt = 0; jt < 4; ++jt)
#pragma unroll
      for (int e = 0; e < 4; ++e) m = fmaxf(m, c[jt][it][e]);
    m = fmaxf(m, __shfl_xor(m, 16));
    m = fmaxf(m, __shfl_xor(m, 32));
    float s = 0.f;
#pragma unroll
    for (int jt = 0; jt < 4; ++jt)
#pragma unroll
      for (int e = 0; e < 4; ++e) {
        float p = __expf(c[jt][it][e] - m);
        c[jt][it][e] = p;
        s += p;
      }
    s += __shfl_xor(s, 16);
    s += __shfl_xor(s, 32);
    const float inv = 1.f / s;
#pragma unroll
    for (int jt = 0; jt < 4; ++jt) {
      s16x4 pk;
#pragma unroll
      for (int e = 0; e < 4; ++e) pk[e] = (short)f2bf(c[jt][it][e] * inv);
      pb[jt][it] = pk;
    }
  }

  f32x4 o[2][4];
#pragma unroll
  for (int a = 0; a < 2; ++a)
#pragma unroll
    for (int b2 = 0; b2 < 4; ++b2) o[a][b2] = zero4();

#pragma unroll
  for (int jt = 0; jt < 4; ++jt) {
    s16x4 va[2];
#pragma unroll
    for (int dt = 0; dt < 2; ++dt)
      va[dt] = *(const s16x4*)&Vth[(dt * 16 + lr) * 64 + jt * 16 + 4 * lg];
#pragma unroll
    for (int dt = 0; dt < 2; ++dt)
#pragma unroll
      for (int it = 0; it < 4; ++it)
        o[dt][it] = mfma16(va[dt], pb[jt][it], o[dt][it]);
  }

  unsigned short* ob = attnout + (size_t)window * 64 * 384;
#pragma unroll
  for (int dt = 0; dt < 2; ++dt)
#pragma unroll
    for (int it = 0; it < 4; ++it) {
      s16x4 pk;
#pragma unroll
      for (int e = 0; e < 4; ++e) pk[e] = (short)f2bf(o[dt][it][e]);
      *(s16x4*)&ob[(size_t)(it * 16 + lr) * 384 + h * 32 + dt * 16 + 4 * lg] = pk;
    }
}

extern "C" void kernel_launch(void* const* d_in, const int* in_sizes, int n_in,
                              void* d_out, int out_size, void* d_ws, size_t ws_size,
                              hipStream_t stream) {
  const float* x = (const float*)d_in[0];
  const float* Wqkv = (const float*)d_in[1];
  const float* bqkv = (const float*)d_in[2];
  const float* Wm = (const float*)d_in[3];
  const float* bm = (const float*)d_in[4];
  const float* rel = (const float*)d_in[5];

  const size_t M = 131072;  // B*G*P
  char* ws = (char*)d_ws;
  size_t off = 0;
  unsigned short* qkv = (unsigned short*)(ws + off);   off += M * 1152 * 2;  // 302 MB
  unsigned short* xb = (unsigned short*)(ws + off);    off += M * 384 * 2;   // 100 MB (reused as attnout)
  unsigned short* WqkvT = (unsigned short*)(ws + off); off += 1152 * 384 * 2;
  unsigned short* WmT = (unsigned short*)(ws + off);   off += 384 * 384 * 2;
  float* biasF = (float*)(ws + off);                   off += 12 * 16 * 64 * 4 * 4;
  float* bqkvs = (float*)(ws + off);                   off += 1152 * 4;
  unsigned short* attnout = xb;  // xb is dead after gemm1

  if (ws_size < off) {
    fill_val<<<(out_size + 255) / 256, 256, 0, stream>>>((float*)d_out, out_size, 12345.0f);
    return;
  }

  prep_wqkvT<<<(1152 * 384 + 255) / 256, 256, 0, stream>>>(Wqkv, WqkvT);
  prep_wmT<<<(384 * 384 + 255) / 256, 256, 0, stream>>>(Wm, WmT);
  prep_bqkv<<<5, 256, 0, stream>>>(bqkv, bqkvs);
  prep_biasF<<<48, 256, 0, stream>>>(rel, biasF);
  conv_bf16<<<2048, 256, 0, stream>>>(x, xb);

  gemm_k<true><<<9216, 512, 0, stream>>>(xb, WqkvT, bqkvs, qkv);
  attn_k<<<6144, 256, 0, stream>>>(qkv, biasF, attnout);
  gemm_k<false><<<3072, 512, 0, stream>>>(attnout, WmT, bm, d_out);
}